// Round 1
// baseline (69.486 us; speedup 1.0000x reference)
//
#include <hip/hip_runtime.h>

// Problem: x[b,i,p,j,q,l,r] = sum_k y[b,k,i,j,l] * W[k,0,p,q,r]
// y: (4,64,64,8,8) f32 ; W: (64,1,16,4,4) f32 ; out: (4,1,1024,32,32) f32
// Output scalar index (within fixed b,i): p*1024 + j*128 + q*32 + l*4 + r
// As float4 (over r): idx4 = p*256 + j*32 + q*8 + l, 4096 float4 per (b,i).

__device__ __forceinline__ void fma4(float4& a, float s, const float4& w) {
    a.x += s * w.x; a.y += s * w.y; a.z += s * w.z; a.w += s * w.w;
}

__global__ __launch_bounds__(256, 1) void backproj_kernel(
    const float* __restrict__ y, const float* __restrict__ W,
    float* __restrict__ out)
{
    // ws: [k][pq] float4 over r  (64 KB). Reused as output staging after k-loop.
    __shared__ float4 ws[64 * 64];
    // ys: [k][c] float4 over jl (c = jl/4)  (16 KB)
    __shared__ float4 ys[64 * 16];

    const int tid = threadIdx.x;
    const int blk = blockIdx.x;       // blk = b*64 + i
    const int b   = blk >> 6;
    const int i   = blk & 63;

    // ---- stage W: 4096 float4s, fully coalesced ----
    const float4* Wg4 = (const float4*)W;   // flat idx f = k*64 + pq
    #pragma unroll
    for (int t = 0; t < 16; ++t) {
        int f = tid + t * 256;
        ws[f] = Wg4[f];
    }
    // ---- stage y slice: 1024 float4s ----
    // y flat float4 idx = (b*64 + k)*1024 + i*16 + c
    const float4* yg4 = (const float4*)y;
    #pragma unroll
    for (int t = 0; t < 4; ++t) {
        int f = tid + t * 256;         // f = k*16 + c
        int k = f >> 4, c = f & 15;
        ys[f] = yg4[(b * 64 + k) * 1024 + i * 16 + c];
    }
    __syncthreads();

    // ---- compute: thread = (u, j); u -> pq columns {u, u+32}; j -> 8 l's ----
    const int u = tid & 31;
    const int j = tid >> 5;

    float4 acc[8][2];
    #pragma unroll
    for (int l = 0; l < 8; ++l) {
        acc[l][0] = float4{0.f, 0.f, 0.f, 0.f};
        acc[l][1] = float4{0.f, 0.f, 0.f, 0.f};
    }

    #pragma unroll 4
    for (int k = 0; k < 64; ++k) {
        float4 wa = ws[k * 64 + u];
        float4 wb = ws[k * 64 + 32 + u];
        float4 ya = ys[k * 16 + j * 2];
        float4 yb = ys[k * 16 + j * 2 + 1];
        float yl[8] = {ya.x, ya.y, ya.z, ya.w, yb.x, yb.y, yb.z, yb.w};
        #pragma unroll
        for (int l = 0; l < 8; ++l) {
            fma4(acc[l][0], yl[l], wa);
            fma4(acc[l][1], yl[l], wb);
        }
    }

    __syncthreads();   // everyone done reading ws -> reuse as staging

    // ---- stage output tile in LDS (xor-swizzled to balance banks) ----
    #pragma unroll
    for (int s = 0; s < 2; ++s) {
        int pq = u + s * 32;
        int p = pq >> 2, q = pq & 3;
        int base = p * 256 + j * 32 + q * 8;
        #pragma unroll
        for (int l = 0; l < 8; ++l) {
            int idx = base + l;
            ws[idx ^ ((idx >> 3) & 7)] = acc[l][s];
        }
    }
    __syncthreads();

    // ---- coalesced store: 4096 consecutive float4s = 64 KB contiguous ----
    float4* og4 = (float4*)out + (size_t)blk * 4096;
    #pragma unroll
    for (int s = 0; s < 16; ++s) {
        int idx = tid + s * 256;
        og4[idx] = ws[idx ^ ((idx >> 3) & 7)];
    }
}

extern "C" void kernel_launch(void* const* d_in, const int* in_sizes, int n_in,
                              void* d_out, int out_size, void* d_ws, size_t ws_size,
                              hipStream_t stream) {
    const float* y = (const float*)d_in[0];   // 4*64*64*8*8 = 1048576
    const float* W = (const float*)d_in[1];   // 64*1*16*4*4 = 16384
    float* out = (float*)d_out;               // 4*1*1024*32*32 = 4194304
    backproj_kernel<<<dim3(256), dim3(256), 0, stream>>>(y, W, out);
}

// Round 2
// 68.564 us; speedup vs baseline: 1.0134x; 1.0134x over previous
//
#include <hip/hip_runtime.h>

// x[b,i,p,j,q,l,r] = sum_k y[b,k,i,j,l] * W[k,0,p,q,r]
// y: (4,64,64,8,8) f32 ; W: (64,1,16,4,4) f32 ; out: (4,1,1024,32,32) f32
// Output float4 index (over r) within fixed (b,i): idx4 = p*256 + j*32 + q*8 + l.
//
// Grid: 1024 blocks = (b,i) x p-quarter. 256 thr. LDS 32KB -> 4-5 blocks/CU,
// 16+ waves/CU (R0 had 1 block/CU = 4 waves -> latency-bound everywhere).

__device__ __forceinline__ void fma4(float4& a, float s, const float4& w) {
    a.x += s * w.x; a.y += s * w.y; a.z += s * w.z; a.w += s * w.w;
}

__global__ __launch_bounds__(256, 4) void backproj_kernel(
    const float* __restrict__ y, const float* __restrict__ W,
    float* __restrict__ out)
{
    // ws: [k][v] float4 over r, v = pq within quarter (16). 16 KB.
    //     Reused as output staging tile (1024 float4 = 16 KB) after k-loop.
    __shared__ float4 ws[64 * 16];
    // ys: [k][c] float4 over jl (c = jl/4). 16 KB.
    __shared__ float4 ys[64 * 16];

    const int tid = threadIdx.x;
    const int blk = blockIdx.x;          // blk = (b*64+i)*4 + qtr
    const int bi  = blk >> 2;
    const int qtr = blk & 3;             // p in [qtr*4, qtr*4+4)
    const int b   = bi >> 6;
    const int i   = bi & 63;

    // ---- stage W quarter: 1024 float4s, coalesced (256B runs) ----
    const float4* Wg4 = (const float4*)W;   // flat f = k*64 + pq
    #pragma unroll
    for (int t = 0; t < 4; ++t) {
        int f = tid + t * 256;              // f = k*16 + v
        ws[f] = Wg4[(f >> 4) * 64 + qtr * 16 + (f & 15)];
    }
    // ---- stage y slice: 1024 float4s (256B runs per k) ----
    const float4* yg4 = (const float4*)y;   // flat f4 = (b*64+k)*1024 + i*16 + c
    #pragma unroll
    for (int t = 0; t < 4; ++t) {
        int f = tid + t * 256;              // f = k*16 + c
        ys[f] = yg4[(b * 64 + (f >> 4)) * 1024 + i * 16 + (f & 15)];
    }
    __syncthreads();

    // ---- compute: thread = (u, g); u -> 1 pq column, g -> 4 jl rows ----
    const int u = tid & 15;              // pq within quarter
    const int g = tid >> 4;              // jl group: jl = g*4 + m

    float4 acc[4];
    #pragma unroll
    for (int m = 0; m < 4; ++m) acc[m] = float4{0.f, 0.f, 0.f, 0.f};

    #pragma unroll 8
    for (int k = 0; k < 64; ++k) {
        float4 w  = ws[k * 16 + u];      // 16 distinct addrs, 4-way broadcast
        float4 yv = ys[k * 16 + g];      // 4 distinct addrs, 16-way broadcast
        fma4(acc[0], yv.x, w);
        fma4(acc[1], yv.y, w);
        fma4(acc[2], yv.z, w);
        fma4(acc[3], yv.w, w);
    }

    __syncthreads();   // done reading ws -> reuse as output staging

    // ---- stage output tile (swizzled), then fully coalesced store ----
    {
        int pl = u >> 2, q = u & 3;
        #pragma unroll
        for (int m = 0; m < 4; ++m) {
            int jl = g * 4 + m, j = jl >> 3, l = jl & 7;
            int lidx = pl * 256 + j * 32 + q * 8 + l;     // [0,1024)
            ws[lidx ^ ((lidx >> 3) & 7)] = acc[m];
        }
    }
    __syncthreads();

    float4* og4 = (float4*)out + (size_t)bi * 4096 + qtr * 1024;
    #pragma unroll
    for (int t = 0; t < 4; ++t) {
        int idx = tid + t * 256;
        og4[idx] = ws[idx ^ ((idx >> 3) & 7)];
    }
}

extern "C" void kernel_launch(void* const* d_in, const int* in_sizes, int n_in,
                              void* d_out, int out_size, void* d_ws, size_t ws_size,
                              hipStream_t stream) {
    const float* y = (const float*)d_in[0];   // 4*64*64*8*8 = 1048576
    const float* W = (const float*)d_in[1];   // 64*1*16*4*4 = 16384
    float* out = (float*)d_out;               // 4*1*1024*32*32 = 4194304
    backproj_kernel<<<dim3(1024), dim3(256), 0, stream>>>(y, W, out);
}